// Round 12
// baseline (1465.023 us; speedup 1.0000x reference)
//
#include <hip/hip_runtime.h>

#define NUM_SEG 256
#define WAY 2
#define NCH 128
#define CHB 64                       // channels per block (ch-split)
#define HW 65536                     // 256*256
#define N_IMG 8
#define PIX_PER_BLK 2048
#define CHUNKS_PER_IMG 32
#define NTHREADS 1024
#define TOTAL_SEG (N_IMG * NUM_SEG)  // 2048
#define NPART (N_IMG * CHUNKS_PER_IMG)     // 256 partial tiles
#define NBLOCKS (NPART * 2)          // 512 blocks, 2 per CU
#define PART_ELEMS (NUM_SEG * NCH)   // 32768
#define KW 32                        // pixels per K-chunk (MFMA/OH granularity)
#define WIN 64                       // pixels per staging window
#define NWIN (PIX_PER_BLK / WIN)     // 32
#define NITER (PIX_PER_BLK / KW)     // 64
#define LDR 40                       // OH padded row, shorts (80 B)
#define LDA 72                       // At padded row, shorts (144 B, 16B-aligned)
#define SSTR 68                      // strip stride, floats (272 B)

typedef __attribute__((ext_vector_type(8))) short short8;
typedef __attribute__((ext_vector_type(4))) short short4v;
typedef __attribute__((ext_vector_type(16))) float f32x16;

static __device__ __forceinline__ unsigned short f2bf(float f) {
    unsigned int u = __float_as_uint(f);
    unsigned int r = u + 0x7FFFu + ((u >> 16) & 1u);
    return (unsigned short)(r >> 16);
}

static __device__ __forceinline__ short4v cvt4(float4 v) {
    short4v r;
    r[0] = (short)f2bf(v.x); r[1] = (short)f2bf(v.y);
    r[2] = (short)f2bf(v.z); r[3] = (short)f2bf(v.w);
    return r;
}

// One-hot MFMA segment-sum, r11 control flow, 64-px window staging
// (one float4 load + one ds_write_b64 per thread per TWO chunks).
// 16 waves = kg(2) x mg(2) x ng(4); 32x32x16 MFMA, k-split.
__global__ __launch_bounds__(NTHREADS, 8)
void seg_mfma_kernel(const float* __restrict__ img,
                     const int* __restrict__ mask,
                     const int* __restrict__ segs,
                     float* __restrict__ ws_part,      // [NPART][256 seg][128 ch]
                     int* __restrict__ labcnt_g) {     // [TOTAL_SEG][WAY]
    __shared__ __align__(16) unsigned short OH[2][NUM_SEG][LDR]; // 40 KB one-hot B
    __shared__ __align__(16) unsigned short At[2][CHB][LDA];     // 18 KB bf16 A
    __shared__ unsigned char segb[PIX_PER_BLK];                  // 2 KB
    __shared__ int labc[NUM_SEG * WAY];                          // 2 KB
    // 63.5 KB -> 2 blocks/CU

    // XCD swizzle: round-robin XCD assignment + this remap => XCD x owns image x
    const int bid0  = blockIdx.x;
    const int bid   = (bid0 & 7) * (NBLOCKS / 8) + (bid0 >> 3);
    const int h     = bid & 1;
    const int chunk = (bid >> 1) & 31;
    const int n     = bid >> 6;
    const int t     = threadIdx.x;
    const int lane  = t & 63;
    const int w     = t >> 6;            // wave 0..15
    const int kg    = w & 1;             // k-half within a 32-px chunk
    const int mg    = (w >> 1) & 1;      // ch tile base 32*mg
    const int ng    = w >> 2;            // seg group base 64*ng
    const int l31   = lane & 31;
    const int h5    = lane >> 5;         // 0/1
    const int kc    = 16 * kg + 8 * h5;  // short-col of this lane's 8 k's (in chunk)

    const long pixbase = (long)n * HW + chunk * PIX_PER_BLK;

    // zero OH (both buffers incl. pads) + labc
    {
        int4 z; z.x = z.y = z.z = z.w = 0;
        int4* p = (int4*)&OH[0][0][0];
        for (int i = t; i < (2 * NUM_SEG * LDR * 2) / 16; i += NTHREADS) p[i] = z;
        if (h == 0)
            for (int i = t; i < NUM_SEG * WAY; i += NTHREADS) labc[i] = 0;
    }
    __syncthreads();

    // stage seg ids (u8); h==0 blocks also build the label histogram
    for (int p = t; p < PIX_PER_BLK; p += NTHREADS) {
        int s = segs[pixbase + p];
        segb[p] = (unsigned char)s;
        if (h == 0) atomicAdd(&labc[s * 2 + mask[pixbase + p]], 1);
    }

    // A staging: 16 threads/row, float4 each -> 64 px/window, 256 B/row contiguous
    const int arow = t >> 4;             // 0..63
    const int ac4  = (t & 15) * 4;       // 0..60 (floats within window)
    const float* gA = img + (long)(n * NCH + h * CHB + arow) * HW
                          + chunk * PIX_PER_BLK + ac4;

    // load window 0
    float4 fc = *(const float4*)(gA);
    __syncthreads();                      // segb + OH zeros visible

    // build window 0 into At[0], chunk-0 one-hot into OH[0]
    *(short4v*)&At[0][arow][ac4] = cvt4(fc);
    const bool sc = (t < KW);             // wave-0 lanes 0..31 own one-hot cols
    int s_prev = -1, s_cur = -1;
    if (sc) {
        s_cur = segb[t];
        OH[0][s_cur][t] = 0x3F80;         // bf16 1.0
    }
    fc = *(const float4*)(gA + WIN);      // window 1
    __syncthreads();                      // At[0], OH[0] visible

    f32x16 acc0 = {};                     // segs 64*ng +  0..31
    f32x16 acc1 = {};                     // segs 64*ng + 32..63

    for (int wi = 0; wi < NWIN; ++wi) {
        const int aw = wi & 1;

        // issue load for window wi+2 (clamped; redundant tail loads harmless)
        const int wnext = (wi + 2 < NWIN) ? (wi + 2) : (NWIN - 1);
        float4 fn = *(const float4*)(gA + wnext * WIN);

        // ---- sub-iter 0: chunk it0 = 2*wi (OH[0], At half 0) ----
        {
            const int it = 2 * wi;
            int s_next = 0;
            if (sc) s_next = segb[(it + 1) * KW + t];   // it+1 < 64 always

            short8 a  = *(const short8*)&At[aw][32 * mg + l31][kc];
            short8 b0 = *(const short8*)&OH[0][64 * ng      + l31][kc];
            short8 b1 = *(const short8*)&OH[0][64 * ng + 32 + l31][kc];
            acc0 = __builtin_amdgcn_mfma_f32_32x32x16_bf16(a, b0, acc0, 0, 0, 0);
            acc1 = __builtin_amdgcn_mfma_f32_32x32x16_bf16(a, b1, acc1, 0, 0, 0);

            // stage window wi+1 (once per window)
            if (wi + 1 < NWIN)
                *(short4v*)&At[aw ^ 1][arow][ac4] = cvt4(fc);
            // scatter chunk it+1 into OH[1]
            if (sc) {
                if (s_prev >= 0 && s_prev != s_next) OH[1][s_prev][t] = 0;
                OH[1][s_next][t] = 0x3F80;
                s_prev = s_cur;
                s_cur  = s_next;
            }
            __syncthreads();
        }

        // ---- sub-iter 1: chunk it1 = 2*wi+1 (OH[1], At half 1) ----
        {
            const int it = 2 * wi + 1;
            int s_next = 0;
            if (sc && it + 1 < NITER) s_next = segb[(it + 1) * KW + t];

            short8 a  = *(const short8*)&At[aw][32 * mg + l31][32 + kc];
            short8 b0 = *(const short8*)&OH[1][64 * ng      + l31][kc];
            short8 b1 = *(const short8*)&OH[1][64 * ng + 32 + l31][kc];
            acc0 = __builtin_amdgcn_mfma_f32_32x32x16_bf16(a, b0, acc0, 0, 0, 0);
            acc1 = __builtin_amdgcn_mfma_f32_32x32x16_bf16(a, b1, acc1, 0, 0, 0);

            // scatter chunk it+1 into OH[0]
            if (sc && it + 1 < NITER) {
                if (s_prev >= 0 && s_prev != s_next) OH[0][s_prev][t] = 0;
                OH[0][s_next][t] = 0x3F80;
                s_prev = s_cur;
                s_cur  = s_next;
            }
            __syncthreads();
        }
        fc = fn;
    }

    // epilogue: strip[2 kg][64 seg][SSTR] fp32 (34.8 KB, reuse OH), 4 rounds.
    // D layout: col(seg-local)=l31, row(ch-local)=(reg&3)+8*(reg>>2)+4*h5.
    float* strip = (float*)&OH[0][0][0];
    float* wsb = ws_part + (long)(n * CHUNKS_PER_IMG + chunk) * PART_ELEMS;
    for (int ngp = 0; ngp < 4; ++ngp) {
        if (ng == ngp) {
            #pragma unroll
            for (int nj = 0; nj < 2; ++nj) {
                #pragma unroll
                for (int q = 0; q < 4; ++q) {
                    float4 v;
                    if (nj == 0) {
                        v.x = acc0[4 * q + 0]; v.y = acc0[4 * q + 1];
                        v.z = acc0[4 * q + 2]; v.w = acc0[4 * q + 3];
                    } else {
                        v.x = acc1[4 * q + 0]; v.y = acc1[4 * q + 1];
                        v.z = acc1[4 * q + 2]; v.w = acc1[4 * q + 3];
                    }
                    const int idx = (kg * 64 + 32 * nj + l31) * SSTR
                                  + 32 * mg + 8 * q + 4 * h5;
                    *(float4*)&strip[idx] = v;
                }
            }
        }
        __syncthreads();
        {   // copy-out with kg-reduce: row = seg-local, 16 thr/row x float4
            const int row = t >> 4;          // 0..63
            const int off = (t & 15) * 4;    // 0..60
            float4 va = *(const float4*)&strip[row * SSTR + off];
            float4 vb = *(const float4*)&strip[(64 + row) * SSTR + off];
            float4 o; o.x = va.x + vb.x; o.y = va.y + vb.y;
            o.z = va.z + vb.z; o.w = va.w + vb.w;
            float* dst = wsb + (long)(64 * ngp + row) * NCH + h * CHB + off;
            *(float4*)dst = o;
        }
        __syncthreads();
    }

    if (h == 0)
        for (int i = t; i < NUM_SEG * WAY; i += NTHREADS)
            atomicAdd(&labcnt_g[n * NUM_SEG * WAY + i], labc[i]);
}

// sum 32 chunk-partials, divide by count, emit labels
__global__ void reduce_ws_kernel(const float* __restrict__ ws_part,
                                 const int* __restrict__ labcnt,
                                 float* __restrict__ out) {
    const int nmean = TOTAL_SEG * NCH;    // 262144
    int i = blockIdx.x * blockDim.x + threadIdx.x;
    if (i < nmean) {
        int nimg = i >> 15;               // / 32768
        int rem  = i & 32767;             // s*128 + c
        const float* base = ws_part + (long)nimg * 32 * PART_ELEMS + rem;
        float acc = 0.0f;
        #pragma unroll
        for (int j = 0; j < CHUNKS_PER_IMG; ++j)
            acc += base[(long)j * PART_ELEMS];
        int g  = i >> 7;                  // n*256 + s
        int c0 = labcnt[g * 2 + 0];
        int c1 = labcnt[g * 2 + 1];
        out[i] = acc / fmaxf((float)(c0 + c1), 1.0f);
    } else if (i < nmean + TOTAL_SEG) {
        int g = i - nmean;
        out[i] = (labcnt[g * 2 + 1] > labcnt[g * 2 + 0]) ? 1.0f : 0.0f;
    }
}

extern "C" void kernel_launch(void* const* d_in, const int* in_sizes, int n_in,
                              void* d_out, int out_size, void* d_ws, size_t ws_size,
                              hipStream_t stream) {
    const float* img  = (const float*)d_in[0];   // (8,128,256,256) f32
    const int*   mask = (const int*)d_in[1];     // (8,256,256) i32 in [0,2)
    const int*   segs = (const int*)d_in[2];     // (8,256,256) i32 in [0,256)

    float* out = (float*)d_out;

    const size_t part_bytes = (size_t)NPART * PART_ELEMS * sizeof(float); // 32 MB
    float* ws_part = (float*)d_ws;
    int*   labcnt  = (int*)((char*)d_ws + part_bytes);

    hipMemsetAsync(labcnt, 0, (size_t)TOTAL_SEG * WAY * sizeof(int), stream);

    seg_mfma_kernel<<<NBLOCKS, NTHREADS, 0, stream>>>(
        img, mask, segs, ws_part, labcnt);

    const int totalThreads = TOTAL_SEG * NCH + TOTAL_SEG;   // 264192
    reduce_ws_kernel<<<(totalThreads + 255) / 256, 256, 0, stream>>>(
        ws_part, labcnt, out);
}

// Round 13
// 84.119 us; speedup vs baseline: 17.4162x; 17.4162x over previous
//
#include <hip/hip_runtime.h>

#define NUM_SEG 256
#define WAY 2
#define NCH 128
#define CHB 64                       // channels per block (ch-split)
#define HW 65536                     // 256*256
#define N_IMG 8
#define PIX_PER_BLK 2048
#define CHUNKS_PER_IMG 32
#define NTHREADS 1024
#define TOTAL_SEG (N_IMG * NUM_SEG)  // 2048
#define NPART (N_IMG * CHUNKS_PER_IMG)     // 256 partial tiles
#define NBLOCKS (NPART * 2)          // 512 blocks, 2 per CU
#define PART_ELEMS (NUM_SEG * NCH)   // 32768
#define KW 32                        // pixels per K-chunk
#define NITER (PIX_PER_BLK / KW)     // 64
#define LDR 40                       // padded row, shorts (80 B, 16B-aligned)
#define SSTR 68                      // strip stride, floats (272 B)

typedef __attribute__((ext_vector_type(8))) short short8;
typedef __attribute__((ext_vector_type(2))) short short2v;
typedef __attribute__((ext_vector_type(16))) float f32x16;

static __device__ __forceinline__ unsigned short f2bf(float f) {
    unsigned int u = __float_as_uint(f);
    unsigned int r = u + 0x7FFFu + ((u >> 16) & 1u);
    return (unsigned short)(r >> 16);
}

static __device__ __forceinline__ short2v cvt2(float2 v) {
    short2v r;
    r[0] = (short)f2bf(v.x); r[1] = (short)f2bf(v.y);
    return r;
}

// One-hot MFMA segment-sum, r11 structure (proven), + XCD-swizzle remap.
// Block (n, chunk, h): C[ch in h*64..h*64+64)][seg] over 2048 px.
// 16 waves = kg(2) x mg(2) x ng(4); wave: 32ch x 64seg x k-half.
__global__ __launch_bounds__(NTHREADS, 8)
void seg_mfma_kernel(const float* __restrict__ img,
                     const int* __restrict__ mask,
                     const int* __restrict__ segs,
                     float* __restrict__ ws_part,      // [NPART][256 seg][128 ch]
                     int* __restrict__ labcnt_g) {     // [TOTAL_SEG][WAY]
    __shared__ __align__(16) unsigned short OH[2][NUM_SEG][LDR]; // 40 KB one-hot B
    __shared__ __align__(16) unsigned short At[2][CHB][LDR];     // 10 KB bf16 A
    __shared__ unsigned char segb[PIX_PER_BLK];                  // 2 KB
    __shared__ int labc[NUM_SEG * WAY];                          // 2 KB
    // 54 KB -> 2 blocks/CU

    // XCD swizzle (bijective, NBLOCKS % 8 == 0): XCD x owns image x;
    // h-pair blocks (shared segs/mask) stay on one XCD's L2.
    const int bid0  = blockIdx.x;
    const int bid   = (bid0 & 7) * (NBLOCKS / 8) + (bid0 >> 3);
    const int h     = bid & 1;
    const int chunk = (bid >> 1) & 31;
    const int n     = bid >> 6;
    const int t     = threadIdx.x;
    const int lane  = t & 63;
    const int w     = t >> 6;            // wave 0..15
    const int kg    = w & 1;             // k-half: k in [16*kg, 16*kg+16)
    const int mg    = (w >> 1) & 1;      // ch tile base 32*mg
    const int ng    = w >> 2;            // seg group base 64*ng
    const int l31   = lane & 31;
    const int h5    = lane >> 5;         // 0/1
    const int kc    = 16 * kg + 8 * h5;  // short-col of this lane's 8 k's

    const long pixbase = (long)n * HW + chunk * PIX_PER_BLK;

    // zero OH (both buffers incl. pads) + labc
    {
        int4 z; z.x = z.y = z.z = z.w = 0;
        int4* p = (int4*)&OH[0][0][0];
        for (int i = t; i < (2 * NUM_SEG * LDR * 2) / 16; i += NTHREADS) p[i] = z;
        if (h == 0)
            for (int i = t; i < NUM_SEG * WAY; i += NTHREADS) labc[i] = 0;
    }
    __syncthreads();

    // stage seg ids (u8); h==0 blocks also build the label histogram
    for (int p = t; p < PIX_PER_BLK; p += NTHREADS) {
        int s = segs[pixbase + p];
        segb[p] = (unsigned char)s;
        if (h == 0) atomicAdd(&labc[s * 2 + mask[pixbase + p]], 1);
    }

    // A staging: 16 threads/row, float2 each (32 px/chunk, 128 B/row contiguous)
    const int arow = t >> 4;             // 0..63
    const int acol = (t & 15) * 2;       // 0..30
    const float* gA = img + (long)(n * NCH + h * CHB + arow) * HW
                          + chunk * PIX_PER_BLK + acol;

    // load chunk 0
    float2 fc = *(const float2*)(gA);
    __syncthreads();                      // segb + OH zeros visible

    // build chunk 0 into At[0], OH[0]
    *(short2v*)&At[0][arow][acol] = cvt2(fc);
    const bool sc = (t < KW);             // wave-0 lanes 0..31 own one-hot cols
    int s_prev = -1, s_cur = -1;
    if (sc) {
        s_cur = segb[t];
        OH[0][s_cur][t] = 0x3F80;         // bf16 1.0
    }
    fc = *(const float2*)(gA + KW);       // issue load chunk 1
    __syncthreads();                      // At[0], OH[0] visible

    f32x16 acc0 = {};                     // segs 64*ng +  0..31
    f32x16 acc1 = {};                     // segs 64*ng + 32..63

    for (int it = 0; it < NITER; ++it) {
        const int cur = it & 1, nxt = cur ^ 1;

        // issue load for chunk it+2 (consumed next iteration)
        float2 fn = fc;
        if (it + 2 < NITER) fn = *(const float2*)(gA + (it + 2) * KW);
        int s_next = 0;
        if (sc && it + 1 < NITER) s_next = segb[(it + 1) * KW + t];

        // MFMA on chunk it: 1 A-frag + 2 B-frags -> 2 MFMAs (32x32x16)
        short8 a  = *(const short8*)&At[cur][32 * mg + l31][kc];
        short8 b0 = *(const short8*)&OH[cur][64 * ng      + l31][kc];
        short8 b1 = *(const short8*)&OH[cur][64 * ng + 32 + l31][kc];
        acc0 = __builtin_amdgcn_mfma_f32_32x32x16_bf16(a, b0, acc0, 0, 0, 0);
        acc1 = __builtin_amdgcn_mfma_f32_32x32x16_bf16(a, b1, acc1, 0, 0, 0);

        // stage chunk it+1 into nxt buffers (disjoint from cur)
        if (it + 1 < NITER) {
            *(short2v*)&At[nxt][arow][acol] = cvt2(fc);
            if (sc) {
                if (s_prev >= 0 && s_prev != s_next) OH[nxt][s_prev][t] = 0;
                OH[nxt][s_next][t] = 0x3F80;
                s_prev = s_cur;
                s_cur  = s_next;
            }
        }
        __syncthreads();
        fc = fn;
    }

    // epilogue: strip[2 kg][64 seg][SSTR] fp32 (34.8 KB, reuse OH), 4 rounds.
    // D layout: col(seg-local)=l31, row(ch-local)=(reg&3)+8*(reg>>2)+4*h5.
    float* strip = (float*)&OH[0][0][0];
    float* wsb = ws_part + (long)(n * CHUNKS_PER_IMG + chunk) * PART_ELEMS;
    for (int ngp = 0; ngp < 4; ++ngp) {
        if (ng == ngp) {
            #pragma unroll
            for (int nj = 0; nj < 2; ++nj) {
                #pragma unroll
                for (int q = 0; q < 4; ++q) {
                    float4 v;
                    if (nj == 0) {
                        v.x = acc0[4 * q + 0]; v.y = acc0[4 * q + 1];
                        v.z = acc0[4 * q + 2]; v.w = acc0[4 * q + 3];
                    } else {
                        v.x = acc1[4 * q + 0]; v.y = acc1[4 * q + 1];
                        v.z = acc1[4 * q + 2]; v.w = acc1[4 * q + 3];
                    }
                    const int idx = (kg * 64 + 32 * nj + l31) * SSTR
                                  + 32 * mg + 8 * q + 4 * h5;
                    *(float4*)&strip[idx] = v;
                }
            }
        }
        __syncthreads();
        {   // copy-out with kg-reduce: row = seg-local, 16 thr/row x float4
            const int row = t >> 4;          // 0..63
            const int off = (t & 15) * 4;    // 0..60
            float4 va = *(const float4*)&strip[row * SSTR + off];
            float4 vb = *(const float4*)&strip[(64 + row) * SSTR + off];
            float4 o; o.x = va.x + vb.x; o.y = va.y + vb.y;
            o.z = va.z + vb.z; o.w = va.w + vb.w;
            float* dst = wsb + (long)(64 * ngp + row) * NCH + h * CHB + off;
            *(float4*)dst = o;
        }
        __syncthreads();
    }

    if (h == 0)
        for (int i = t; i < NUM_SEG * WAY; i += NTHREADS)
            atomicAdd(&labcnt_g[n * NUM_SEG * WAY + i], labc[i]);
}

// sum 32 chunk-partials, divide by count, emit labels
__global__ void reduce_ws_kernel(const float* __restrict__ ws_part,
                                 const int* __restrict__ labcnt,
                                 float* __restrict__ out) {
    const int nmean = TOTAL_SEG * NCH;    // 262144
    int i = blockIdx.x * blockDim.x + threadIdx.x;
    if (i < nmean) {
        int nimg = i >> 15;               // / 32768
        int rem  = i & 32767;             // s*128 + c
        const float* base = ws_part + (long)nimg * 32 * PART_ELEMS + rem;
        float acc = 0.0f;
        #pragma unroll
        for (int j = 0; j < CHUNKS_PER_IMG; ++j)
            acc += base[(long)j * PART_ELEMS];
        int g  = i >> 7;                  // n*256 + s
        int c0 = labcnt[g * 2 + 0];
        int c1 = labcnt[g * 2 + 1];
        out[i] = acc / fmaxf((float)(c0 + c1), 1.0f);
    } else if (i < nmean + TOTAL_SEG) {
        int g = i - nmean;
        out[i] = (labcnt[g * 2 + 1] > labcnt[g * 2 + 0]) ? 1.0f : 0.0f;
    }
}

extern "C" void kernel_launch(void* const* d_in, const int* in_sizes, int n_in,
                              void* d_out, int out_size, void* d_ws, size_t ws_size,
                              hipStream_t stream) {
    const float* img  = (const float*)d_in[0];   // (8,128,256,256) f32
    const int*   mask = (const int*)d_in[1];     // (8,256,256) i32 in [0,2)
    const int*   segs = (const int*)d_in[2];     // (8,256,256) i32 in [0,256)

    float* out = (float*)d_out;

    const size_t part_bytes = (size_t)NPART * PART_ELEMS * sizeof(float); // 32 MB
    float* ws_part = (float*)d_ws;
    int*   labcnt  = (int*)((char*)d_ws + part_bytes);

    hipMemsetAsync(labcnt, 0, (size_t)TOTAL_SEG * WAY * sizeof(int), stream);

    seg_mfma_kernel<<<NBLOCKS, NTHREADS, 0, stream>>>(
        img, mask, segs, ws_part, labcnt);

    const int totalThreads = TOTAL_SEG * NCH + TOTAL_SEG;   // 264192
    reduce_ws_kernel<<<(totalThreads + 255) / 256, 256, 0, stream>>>(
        ws_part, labcnt, out);
}

// Round 14
// 66.535 us; speedup vs baseline: 22.0187x; 1.2643x over previous
//
#include <hip/hip_runtime.h>

#define NUM_SEG 256
#define WAY 2
#define NCH 128
#define CHB 64                       // channels per block (ch-split)
#define HW 65536                     // 256*256
#define N_IMG 8
#define PIX_PER_BLK 2048
#define CHUNKS_PER_IMG 32
#define NTHREADS 1024
#define TOTAL_SEG (N_IMG * NUM_SEG)  // 2048
#define NPART (N_IMG * CHUNKS_PER_IMG)     // 256 partial tiles
#define NBLOCKS (NPART * 2)          // 512 blocks, 2 per CU
#define PART_ELEMS (NUM_SEG * NCH)   // 32768
#define KW 32                        // pixels per K-chunk
#define NITER (PIX_PER_BLK / KW)     // 64
#define LDR 40                       // padded row, shorts (80 B, 16B-aligned)
#define SSTR 68                      // strip stride, floats (272 B)

typedef __attribute__((ext_vector_type(8))) short short8;
typedef __attribute__((ext_vector_type(4))) short short4v;
typedef __attribute__((ext_vector_type(2))) short short2v;
typedef __attribute__((ext_vector_type(16))) float f32x16;

static __device__ __forceinline__ unsigned short f2bf(float f) {
    unsigned int u = __float_as_uint(f);
    unsigned int r = u + 0x7FFFu + ((u >> 16) & 1u);
    return (unsigned short)(r >> 16);
}

static __device__ __forceinline__ float bf2f(unsigned short s) {
    unsigned int u = ((unsigned int)s) << 16;
    return __uint_as_float(u);
}

static __device__ __forceinline__ short2v cvt2(float2 v) {
    short2v r;
    r[0] = (short)f2bf(v.x); r[1] = (short)f2bf(v.y);
    return r;
}

// One-hot MFMA segment-sum, r11/r13 structure (proven), bf16 partials.
// Block (n, chunk, h): C[ch in h*64..h*64+64)][seg] over 2048 px.
// 16 waves = kg(2) x mg(2) x ng(4); wave: 32ch x 64seg x k-half.
__global__ __launch_bounds__(NTHREADS, 8)
void seg_mfma_kernel(const float* __restrict__ img,
                     const int* __restrict__ mask,
                     const int* __restrict__ segs,
                     unsigned short* __restrict__ ws_part, // [NPART][256 seg][128 ch] bf16
                     int* __restrict__ labcnt_g) {         // [TOTAL_SEG][WAY]
    __shared__ __align__(16) unsigned short OH[2][NUM_SEG][LDR]; // 40 KB one-hot B
    __shared__ __align__(16) unsigned short At[2][CHB][LDR];     // 10 KB bf16 A
    __shared__ unsigned char segb[PIX_PER_BLK];                  // 2 KB
    __shared__ int labc[NUM_SEG * WAY];                          // 2 KB
    // 54 KB -> 2 blocks/CU

    // XCD swizzle (bijective, NBLOCKS % 8 == 0): XCD x owns image x.
    const int bid0  = blockIdx.x;
    const int bid   = (bid0 & 7) * (NBLOCKS / 8) + (bid0 >> 3);
    const int h     = bid & 1;
    const int chunk = (bid >> 1) & 31;
    const int n     = bid >> 6;
    const int t     = threadIdx.x;
    const int lane  = t & 63;
    const int w     = t >> 6;            // wave 0..15
    const int kg    = w & 1;             // k-half: k in [16*kg, 16*kg+16)
    const int mg    = (w >> 1) & 1;      // ch tile base 32*mg
    const int ng    = w >> 2;            // seg group base 64*ng
    const int l31   = lane & 31;
    const int h5    = lane >> 5;         // 0/1
    const int kc    = 16 * kg + 8 * h5;  // short-col of this lane's 8 k's

    const long pixbase = (long)n * HW + chunk * PIX_PER_BLK;

    // zero OH (both buffers incl. pads) + labc
    {
        int4 z; z.x = z.y = z.z = z.w = 0;
        int4* p = (int4*)&OH[0][0][0];
        for (int i = t; i < (2 * NUM_SEG * LDR * 2) / 16; i += NTHREADS) p[i] = z;
        if (h == 0)
            for (int i = t; i < NUM_SEG * WAY; i += NTHREADS) labc[i] = 0;
    }
    __syncthreads();

    // stage seg ids (u8); h==0 blocks also build the label histogram
    for (int p = t; p < PIX_PER_BLK; p += NTHREADS) {
        int s = segs[pixbase + p];
        segb[p] = (unsigned char)s;
        if (h == 0) atomicAdd(&labc[s * 2 + mask[pixbase + p]], 1);
    }

    // A staging: 16 threads/row, float2 each (32 px/chunk, 128 B/row contiguous)
    const int arow = t >> 4;             // 0..63
    const int acol = (t & 15) * 2;       // 0..30
    const float* gA = img + (long)(n * NCH + h * CHB + arow) * HW
                          + chunk * PIX_PER_BLK + acol;

    // load chunk 0
    float2 fc = *(const float2*)(gA);
    __syncthreads();                      // segb + OH zeros visible

    // build chunk 0 into At[0], OH[0]
    *(short2v*)&At[0][arow][acol] = cvt2(fc);
    const bool sc = (t < KW);             // wave-0 lanes 0..31 own one-hot cols
    int s_prev = -1, s_cur = -1;
    if (sc) {
        s_cur = segb[t];
        OH[0][s_cur][t] = 0x3F80;         // bf16 1.0
    }
    fc = *(const float2*)(gA + KW);       // issue load chunk 1
    __syncthreads();                      // At[0], OH[0] visible

    f32x16 acc0 = {};                     // segs 64*ng +  0..31
    f32x16 acc1 = {};                     // segs 64*ng + 32..63

    for (int it = 0; it < NITER; ++it) {
        const int cur = it & 1, nxt = cur ^ 1;

        // issue load for chunk it+2 (consumed next iteration)
        float2 fn = fc;
        if (it + 2 < NITER) fn = *(const float2*)(gA + (it + 2) * KW);
        int s_next = 0;
        if (sc && it + 1 < NITER) s_next = segb[(it + 1) * KW + t];

        // MFMA on chunk it: 1 A-frag + 2 B-frags -> 2 MFMAs (32x32x16)
        short8 a  = *(const short8*)&At[cur][32 * mg + l31][kc];
        short8 b0 = *(const short8*)&OH[cur][64 * ng      + l31][kc];
        short8 b1 = *(const short8*)&OH[cur][64 * ng + 32 + l31][kc];
        acc0 = __builtin_amdgcn_mfma_f32_32x32x16_bf16(a, b0, acc0, 0, 0, 0);
        acc1 = __builtin_amdgcn_mfma_f32_32x32x16_bf16(a, b1, acc1, 0, 0, 0);

        // stage chunk it+1 into nxt buffers (disjoint from cur)
        if (it + 1 < NITER) {
            *(short2v*)&At[nxt][arow][acol] = cvt2(fc);
            if (sc) {
                if (s_prev >= 0 && s_prev != s_next) OH[nxt][s_prev][t] = 0;
                OH[nxt][s_next][t] = 0x3F80;
                s_prev = s_cur;
                s_cur  = s_next;
            }
        }
        __syncthreads();
        fc = fn;
    }

    // epilogue: strip[2 kg][64 seg][SSTR] fp32 (34.8 KB, reuse OH), 4 rounds.
    // D layout: col(seg-local)=l31, row(ch-local)=(reg&3)+8*(reg>>2)+4*h5.
    float* strip = (float*)&OH[0][0][0];
    unsigned short* wsb = ws_part + (long)(n * CHUNKS_PER_IMG + chunk) * PART_ELEMS;
    for (int ngp = 0; ngp < 4; ++ngp) {
        if (ng == ngp) {
            #pragma unroll
            for (int nj = 0; nj < 2; ++nj) {
                #pragma unroll
                for (int q = 0; q < 4; ++q) {
                    float4 v;
                    if (nj == 0) {
                        v.x = acc0[4 * q + 0]; v.y = acc0[4 * q + 1];
                        v.z = acc0[4 * q + 2]; v.w = acc0[4 * q + 3];
                    } else {
                        v.x = acc1[4 * q + 0]; v.y = acc1[4 * q + 1];
                        v.z = acc1[4 * q + 2]; v.w = acc1[4 * q + 3];
                    }
                    const int idx = (kg * 64 + 32 * nj + l31) * SSTR
                                  + 32 * mg + 8 * q + 4 * h5;
                    *(float4*)&strip[idx] = v;
                }
            }
        }
        __syncthreads();
        {   // copy-out with kg-reduce, bf16 pack: 16 thr/row x 4 ch each
            const int row = t >> 4;          // 0..63 (seg-local)
            const int off = (t & 15) * 4;    // 0..60
            float4 va = *(const float4*)&strip[row * SSTR + off];
            float4 vb = *(const float4*)&strip[(64 + row) * SSTR + off];
            short4v o;
            o[0] = (short)f2bf(va.x + vb.x);
            o[1] = (short)f2bf(va.y + vb.y);
            o[2] = (short)f2bf(va.z + vb.z);
            o[3] = (short)f2bf(va.w + vb.w);
            unsigned short* dst = wsb + (long)(64 * ngp + row) * NCH + h * CHB + off;
            *(short4v*)dst = o;
        }
        __syncthreads();
    }

    if (h == 0)
        for (int i = t; i < NUM_SEG * WAY; i += NTHREADS)
            atomicAdd(&labcnt_g[n * NUM_SEG * WAY + i], labc[i]);
}

// sum 32 bf16 chunk-partials, divide by count, emit labels
__global__ void reduce_ws_kernel(const unsigned short* __restrict__ ws_part,
                                 const int* __restrict__ labcnt,
                                 float* __restrict__ out) {
    const int nmean = TOTAL_SEG * NCH;    // 262144
    int i = blockIdx.x * blockDim.x + threadIdx.x;
    if (i < nmean) {
        int nimg = i >> 15;               // / 32768
        int rem  = i & 32767;             // s*128 + c
        const unsigned short* base = ws_part + (long)nimg * 32 * PART_ELEMS + rem;
        float acc = 0.0f;
        #pragma unroll
        for (int j = 0; j < CHUNKS_PER_IMG; ++j)
            acc += bf2f(base[(long)j * PART_ELEMS]);
        int g  = i >> 7;                  // n*256 + s
        int c0 = labcnt[g * 2 + 0];
        int c1 = labcnt[g * 2 + 1];
        out[i] = acc / fmaxf((float)(c0 + c1), 1.0f);
    } else if (i < nmean + TOTAL_SEG) {
        int g = i - nmean;
        out[i] = (labcnt[g * 2 + 1] > labcnt[g * 2 + 0]) ? 1.0f : 0.0f;
    }
}

extern "C" void kernel_launch(void* const* d_in, const int* in_sizes, int n_in,
                              void* d_out, int out_size, void* d_ws, size_t ws_size,
                              hipStream_t stream) {
    const float* img  = (const float*)d_in[0];   // (8,128,256,256) f32
    const int*   mask = (const int*)d_in[1];     // (8,256,256) i32 in [0,2)
    const int*   segs = (const int*)d_in[2];     // (8,256,256) i32 in [0,256)

    float* out = (float*)d_out;

    const size_t part_bytes = (size_t)NPART * PART_ELEMS * sizeof(unsigned short); // 16 MB
    unsigned short* ws_part = (unsigned short*)d_ws;
    int* labcnt = (int*)((char*)d_ws + part_bytes);

    hipMemsetAsync(labcnt, 0, (size_t)TOTAL_SEG * WAY * sizeof(int), stream);

    seg_mfma_kernel<<<NBLOCKS, NTHREADS, 0, stream>>>(
        img, mask, segs, ws_part, labcnt);

    const int totalThreads = TOTAL_SEG * NCH + TOTAL_SEG;   // 264192
    reduce_ws_kernel<<<(totalThreads + 255) / 256, 256, 0, stream>>>(
        ws_part, labcnt, out);
}